// Round 3
// baseline (167.719 us; speedup 1.0000x reference)
//
#include <hip/hip_runtime.h>
#include <stdint.h>

// ---------------------------------------------------------------------------
// WideAndDeep: B=16384, F=3, C=256, D=64, H=1024, ND=13
// R17: peel the final K-iteration in the 8-phase GEMM template. The old
// wrap-around staged 3 dead tiles (96 KB/block, ~25 MB HBM re-fetch in gemm2
// since tile-0 rows are L2-evicted 15 tiles later). Peeled tail stages only
// A.O (within-iteration dependency), computes E phases barrier-free, then
// one vmcnt(0)+barrier before O phases. Bit-identical accumulation order.
// Both GEMMs on the 256x256 8-phase schedule (T2 swizzle + T3/T4 counted
// vmcnt(4) + T5 setprio + T1 XCD swizzle). GEMM1 K padded 205->256.
// 8-phase stage order per loop iter:
//   p1:A.O.h0  p2:A.O.h1  p3:B.E.h0  p4:B.E.h1[vmcnt4]
//   p5:A.E.h0  p6:A.E.h1  p7:B.O.h0  p8:B.O.h1[vmcnt4]
// FIFO: vmcnt(4)@p4 retires {B.O prev, A.O} (read p5-p8); vmcnt(4)@p8
// retires {B.E,A.E next} (read next p1-p4); tail entry has <=4 (B.O final).
// ---------------------------------------------------------------------------

#define BATCH 16384
#define HDIM 1024
#define K1 256
#define DEEP_IN 205

typedef short bf16x8 __attribute__((ext_vector_type(8)));
typedef float f32x4 __attribute__((ext_vector_type(4)));
typedef uint16_t u16x8 __attribute__((ext_vector_type(8)));
typedef uint16_t u16x4 __attribute__((ext_vector_type(4)));

__device__ __forceinline__ uint16_t f2bf(float f) {
    uint32_t x;
    __builtin_memcpy(&x, &f, 4);
    uint32_t r = (x + 0x7fffu + ((x >> 16) & 1u)) >> 16;
    return (uint16_t)r;
}

__device__ __forceinline__ void async_ld16(const uint16_t* g, uint16_t* l) {
    __builtin_amdgcn_global_load_lds(
        (const __attribute__((address_space(1))) uint32_t*)g,
        (__attribute__((address_space(3))) uint32_t*)l, 16, 0, 0);
}

// ---------------------------------------------------------------------------
// prep: everything the GEMMs need, one 256-thread elementwise kernel.
//   [0, 2048)    : deep_x [B][256] bf16 (x8), cols 205..255 = 0
//   [2048, 2176) : W1 -> bf16, 205 -> 256 K-pad (x8)
//   [2176, 2688) : W2 -> bf16 (x8)
//   [2688, 2752) : wide path (sparse gathers + dense dot) + b3 seed
// ---------------------------------------------------------------------------
__global__ __launch_bounds__(256) void prep_kernel(
    const int* __restrict__ sp, const float* __restrict__ dense,
    const float* __restrict__ emb, const float* __restrict__ W1,
    const float* __restrict__ W2, const float* __restrict__ ww,
    const float* __restrict__ wb, const float* __restrict__ b3,
    uint16_t* __restrict__ dx, uint16_t* __restrict__ W1b,
    uint16_t* __restrict__ W2b, float* __restrict__ wide)
{
    const int bid = blockIdx.x;
    const int tid = threadIdx.x;
    if (bid < 2048) {                      // ---- deep_x build (16384 x 32 vec8)
        int idx = bid * 256 + tid;         // < 524288
        int b = idx >> 5, c0 = (idx & 31) * 8;
        u16x8 o;
        if (c0 < 192) {
            int f = c0 >> 6, cc = c0 & 63;
            int s = sp[b * 3 + f];
            const float* e = emb + (size_t)(((f << 8) + s) * 64 + cc);
            float4 v0 = *(const float4*)e;
            float4 v1 = *(const float4*)(e + 4);
            o[0] = f2bf(v0.x); o[1] = f2bf(v0.y); o[2] = f2bf(v0.z); o[3] = f2bf(v0.w);
            o[4] = f2bf(v1.x); o[5] = f2bf(v1.y); o[6] = f2bf(v1.z); o[7] = f2bf(v1.w);
        } else {
#pragma unroll
            for (int t = 0; t < 8; t++) {
                int c = c0 + t;
                o[t] = (c < DEEP_IN) ? f2bf(dense[b * 13 + (c - 192)])
                                     : (uint16_t)0;
            }
        }
        *(u16x8*)(dx + (size_t)b * K1 + c0) = o;
    } else if (bid < 2176) {               // ---- W1 convert, 205 -> 256
        int idx = (bid - 2048) * 256 + tid;    // < 32768
        int n = idx >> 5, c0 = (idx & 31) * 8;
        u16x8 o;
#pragma unroll
        for (int t = 0; t < 8; t++) {
            int c = c0 + t;
            o[t] = (c < DEEP_IN) ? f2bf(W1[n * DEEP_IN + c]) : (uint16_t)0;
        }
        *(u16x8*)(W1b + (size_t)n * K1 + c0) = o;
    } else if (bid < 2688) {               // ---- W2 convert (x8)
        int k = (bid - 2176) * 256 + tid;      // < 131072
        const float* src = W2 + (size_t)k * 8;
        float4 v0 = *(const float4*)src;
        float4 v1 = *(const float4*)(src + 4);
        u16x8 o;
        o[0] = f2bf(v0.x); o[1] = f2bf(v0.y); o[2] = f2bf(v0.z); o[3] = f2bf(v0.w);
        o[4] = f2bf(v1.x); o[5] = f2bf(v1.y); o[6] = f2bf(v1.z); o[7] = f2bf(v1.w);
        *(u16x8*)(W2b + (size_t)k * 8) = o;
    } else {                               // ---- wide path (+ b3 seed)
        int b = (bid - 2688) * 256 + tid;      // < 16384
        int s0 = sp[b * 3], s1 = sp[b * 3 + 1], s2 = sp[b * 3 + 2];
        float w = wb[0] + b3[0];
        w += ww[s0] + ww[256 + s1] + ww[512 + s2];
        w += ww[768    + s0 * 3 + s1];
        w += ww[66304  + s0 * 3 + s2];
        w += ww[131840 + s1 * 3 + s2];
        w += ww[197376 + (s0 * 3 + s1) * 3 + s2];
        const float* wd = ww + 16974592;
        float acc2 = 0.f;
#pragma unroll
        for (int j = 0; j < 13; j++) acc2 += dense[b * 13 + j] * wd[j];
        wide[b] = w + acc2;
    }
}

// ---------------------------------------------------------------------------
// Shared 8-phase GEMM core. 256x256 tile, 8 waves 2m x 4n, wave tile 128x64,
// BK=64, 128 KiB LDS (2 K-tile dbuf). LDS element map: AE=0 AO=16384
// BE=32768 BO=49152; each region [2 halves][128 rows][64 cols], row r's
// column bytes XOR-swizzled by (r&7)<<4 (inverse-swizzled global source,
// linear global_load_lds dest). Raw s_barrier; vmcnt(4) only at p4 & p8.
// ---------------------------------------------------------------------------
#define BAR8() do { asm volatile("" ::: "memory");                             \
    __builtin_amdgcn_s_barrier();                                              \
    asm volatile("" ::: "memory"); } while (0)
#define VM4() asm volatile("s_waitcnt vmcnt(4)" ::: "memory")
#define VM0() asm volatile("s_waitcnt vmcnt(0)" ::: "memory")

#define STG8(grow, regoff, h, kt) do {                                         \
    const uint16_t* g_ = (grow) + (size_t)((h) * 128) * (size_t)K + (kt);      \
    async_ld16(g_, &lds[(regoff) + (h) * 8192 + wave * 512]);                  \
    async_ld16(g_ + (size_t)64 * (size_t)K,                                    \
               &lds[(regoff) + (h) * 8192 + 4096 + wave * 512]);               \
} while (0)

#define LDA8(base, msub) do {                                                  \
    _Pragma("unroll") for (int mt = 0; mt < 4; mt++) {                         \
        int ro_ = (base) + ((msub) * 64 + mt * 16) * 64;                       \
        af[mt][0] = *(const bf16x8*)&lds[ro_ + kc0];                           \
        af[mt][1] = *(const bf16x8*)&lds[ro_ + kc1];                           \
    } } while (0)

#define LDB8(dst, base, nsub) do {                                             \
    _Pragma("unroll") for (int nt = 0; nt < 2; nt++) {                         \
        int ro_ = (base) + ((nsub) * 32 + nt * 16) * 64;                       \
        dst[nt][0] = *(const bf16x8*)&lds[ro_ + kc0];                          \
        dst[nt][1] = *(const bf16x8*)&lds[ro_ + kc1];                          \
    } } while (0)

#define MM8(msub, nsub, BF) do {                                               \
    __builtin_amdgcn_s_setprio(1);                                             \
    _Pragma("unroll") for (int mt = 0; mt < 4; mt++)                           \
    _Pragma("unroll") for (int nt = 0; nt < 2; nt++) {                         \
        acc[(msub)*4+mt][(nsub)*2+nt] = __builtin_amdgcn_mfma_f32_16x16x32_bf16( \
            af[mt][0], BF[nt][0], acc[(msub)*4+mt][(nsub)*2+nt], 0, 0, 0);     \
        acc[(msub)*4+mt][(nsub)*2+nt] = __builtin_amdgcn_mfma_f32_16x16x32_bf16( \
            af[mt][1], BF[nt][1], acc[(msub)*4+mt][(nsub)*2+nt], 0, 0, 0);     \
    }                                                                          \
    __builtin_amdgcn_s_setprio(0); } while (0)

#define GEMM8_DECLS()                                                          \
    const int tid = threadIdx.x;                                               \
    const int lane = tid & 63, wave = tid >> 6;                                \
    const int wm = wave >> 2, wn = wave & 3;                                   \
    const int id = blockIdx.x;                                                 \
    const int wg = (id & 7) * 32 + (id >> 3);                                  \
    const int by = wg >> 2, bx = wg & 3;                                       \
    const int bm = by * 256, bn = bx * 256;                                    \
    const int lam = lane & 15, lad = lane >> 4;                                \
    const int sw = (lane & 7) << 4;                                            \
    const int kc0 = ((lad * 16) ^ sw) >> 1;                                    \
    const int kc1 = ((64 + lad * 16) ^ sw) >> 1;                               \
    const int aBE = wm * 8192 + lam * 64;                                      \
    const int aBO = aBE + 16384;                                               \
    const int bBE = 32768 + (wn >> 1) * 8192 + ((wn & 1) * 64 + lam) * 64;     \
    const int bBO = bBE + 16384;                                               \
    const int trow = tid >> 3;                                                 \
    const int csel = ((tid & 7) ^ (trow & 7)) << 3;

// Main: prologue + (NI-1) full 8-phase iterations + peeled tail.
// Tail: stage A.O only; E phases barrier-free (operands retired at last
// p8 vmcnt(4), regions not written); vmcnt(0)+barrier; O phases.
#define GEMM8_MAIN()                                                           \
    f32x4 acc[8][4];                                                           \
    _Pragma("unroll") for (int i = 0; i < 8; i++)                              \
        _Pragma("unroll") for (int j = 0; j < 4; j++) acc[i][j] = (f32x4)0.f;  \
    bf16x8 af[4][2], bf0[2][2], bf1[2][2];                                     \
    const int NI = K >> 7;                                                     \
    STG8(aRow, 0, 0, 0);     STG8(aRow, 0, 1, 0);                              \
    STG8(bRow, 32768, 0, 0); STG8(bRow, 32768, 1, 0);                          \
    STG8(bRow, 49152, 0, 64); STG8(bRow, 49152, 1, 64);                        \
    VM4();                                                                     \
    BAR8();                                                                    \
    for (int it = 0; it < NI - 1; ++it) {                                      \
        const int k1 = (2 * it + 1) * 64;                                      \
        const int k2 = (2 * it + 2) * 64;                                      \
        const int k3 = (2 * it + 3) * 64;                                      \
        LDA8(aBE, 0); LDB8(bf0, bBE, 0); STG8(aRow, 16384, 0, k1);             \
        BAR8(); MM8(0, 0, bf0); BAR8();                                        \
        LDB8(bf1, bBE, 1); STG8(aRow, 16384, 1, k1);                           \
        BAR8(); MM8(0, 1, bf1); BAR8();                                        \
        LDA8(aBE, 1); STG8(bRow, 32768, 0, k2);                                \
        BAR8(); MM8(1, 1, bf1); BAR8();                                        \
        STG8(bRow, 32768, 1, k2);                                              \
        BAR8(); MM8(1, 0, bf0); VM4(); BAR8();                                 \
        LDA8(aBO, 0); LDB8(bf0, bBO, 0); STG8(aRow, 0, 0, k2);                 \
        BAR8(); MM8(0, 0, bf0); BAR8();                                        \
        LDB8(bf1, bBO, 1); STG8(aRow, 0, 1, k2);                               \
        BAR8(); MM8(0, 1, bf1); BAR8();                                        \
        LDA8(aBO, 1); STG8(bRow, 49152, 0, k3);                                \
        BAR8(); MM8(1, 1, bf1); BAR8();                                        \
        STG8(bRow, 49152, 1, k3);                                              \
        BAR8(); MM8(1, 0, bf0); VM4(); BAR8();                                 \
    }                                                                          \
    {                                                                          \
        const int kL = (2 * NI - 1) * 64;                                      \
        STG8(aRow, 16384, 0, kL); STG8(aRow, 16384, 1, kL);                    \
        LDA8(aBE, 0); LDB8(bf0, bBE, 0); MM8(0, 0, bf0);                       \
        LDB8(bf1, bBE, 1); MM8(0, 1, bf1);                                     \
        LDA8(aBE, 1); MM8(1, 1, bf1); MM8(1, 0, bf0);                          \
        VM0();                                                                 \
        BAR8();                                                                \
        LDA8(aBO, 0); LDB8(bf0, bBO, 0); MM8(0, 0, bf0);                       \
        LDB8(bf1, bBO, 1); MM8(0, 1, bf1);                                     \
        LDA8(aBO, 1); MM8(1, 1, bf1); MM8(1, 0, bf0);                          \
    }

// ---------------------------------------------------------------------------
// gemm1_8: h1 = relu(dxp @ W1b^T + b1), K=256 (zero-padded). B rows staged
// permuted (prow = 4*(t&15) + (t>>4)) so lane lam's acc cols jn map to
// n = bn + wn*64 + 4*lam + jn -> natural-layout u16x4 packed stores.
// ---------------------------------------------------------------------------
__global__ __launch_bounds__(512, 2) void gemm1_8(
    const uint16_t* __restrict__ A, const uint16_t* __restrict__ Bw,
    const float* __restrict__ bias, uint16_t* __restrict__ C,
    int M, int N, int K)
{
    __shared__ __align__(16) uint16_t lds[65536];   // 128 KiB
    GEMM8_DECLS()
    const uint16_t* aRow = A + (size_t)(bm + trow) * K + csel;
    const int prow = 4 * (trow & 15) + (trow >> 4);
    const uint16_t* bRow = Bw + (size_t)(bn + prow) * K + csel;
    GEMM8_MAIN()

    float bv[4];
#pragma unroll
    for (int jn = 0; jn < 4; jn++) bv[jn] = bias[bn + wn * 64 + 4 * lam + jn];
#pragma unroll
    for (int im = 0; im < 8; im++) {
#pragma unroll
        for (int r = 0; r < 4; r++) {
            int m = bm + wm * 128 + im * 16 + lad * 4 + r;
            u16x4 o;
#pragma unroll
            for (int jn = 0; jn < 4; jn++)
                o[jn] = f2bf(fmaxf(acc[im][jn][r] + bv[jn], 0.f));
            *(u16x4*)&C[(size_t)m * N + bn + wn * 64 + 4 * lam] = o;
        }
    }
}

// ---------------------------------------------------------------------------
// gemm_fused8: per-row partial of relu(acc + b2) . W3 -> atomicAdd(outacc).
// (B staged unpermuted; n-permutation irrelevant to the reduction.)
// ---------------------------------------------------------------------------
__global__ __launch_bounds__(512, 2) void gemm_fused8(
    const uint16_t* __restrict__ A, const uint16_t* __restrict__ Bw,
    const float* __restrict__ bias, const float* __restrict__ W3,
    float* __restrict__ outacc, int M, int N, int K)
{
    __shared__ __align__(16) uint16_t lds[65536];   // 128 KiB
    GEMM8_DECLS()
    const uint16_t* aRow = A + (size_t)(bm + trow) * K + csel;
    const uint16_t* bRow = Bw + (size_t)(bn + trow) * K + csel;
    GEMM8_MAIN()

    float bv[4], w3v[4];
#pragma unroll
    for (int jn = 0; jn < 4; jn++) {
        int n = bn + wn * 64 + jn * 16 + lam;
        bv[jn] = bias[n];
        w3v[jn] = W3[n];
    }
#pragma unroll
    for (int im = 0; im < 8; im++) {
#pragma unroll
        for (int r = 0; r < 4; r++) {
            float pt = 0.f;
#pragma unroll
            for (int jn = 0; jn < 4; jn++)
                pt += fmaxf(acc[im][jn][r] + bv[jn], 0.f) * w3v[jn];
            pt += __shfl_xor(pt, 1);
            pt += __shfl_xor(pt, 2);
            pt += __shfl_xor(pt, 4);
            pt += __shfl_xor(pt, 8);
            if (lam == 0) {
                int m = bm + wm * 128 + im * 16 + lad * 4 + r;
                atomicAdd(&outacc[m], pt);
            }
        }
    }
}

// ---------------------------------------------------------------------------
// Sigmoid over the accumulated logits. Grid 64 x 256.
// ---------------------------------------------------------------------------
__global__ __launch_bounds__(256) void sigmoid_kernel(
    const float* __restrict__ outacc, float* __restrict__ out)
{
    int b = blockIdx.x * 256 + threadIdx.x;
    out[b] = 1.f / (1.f + __expf(-outacc[b]));
}

// ---------------------------------------------------------------------------
extern "C" void kernel_launch(void* const* d_in, const int* in_sizes, int n_in,
                              void* d_out, int out_size, void* d_ws, size_t ws_size,
                              hipStream_t stream) {
    const int*   sp    = (const int*)d_in[0];
    const float* dense = (const float*)d_in[1];
    const float* ww    = (const float*)d_in[2];
    const float* wb    = (const float*)d_in[3];
    const float* emb   = (const float*)d_in[4];
    const float* W1    = (const float*)d_in[5];
    const float* b1    = (const float*)d_in[6];
    const float* W2    = (const float*)d_in[7];
    const float* b2    = (const float*)d_in[8];
    const float* W3    = (const float*)d_in[9];
    const float* b3    = (const float*)d_in[10];
    float* out = (float*)d_out;

    char* ws = (char*)d_ws;
    float*    wide = (float*)ws;                       //     65,536 B
    uint16_t* dxp  = (uint16_t*)(ws + 65536);          //  8,388,608 B (16384x256)
    uint16_t* W1b  = (uint16_t*)(ws + 8454144);        //    524,288 B (1024x256)
    uint16_t* W2b  = (uint16_t*)(ws + 8978432);        //  2,097,152 B
    uint16_t* h1   = (uint16_t*)(ws + 11075584);       // 33,554,432 B -> 44,630,016 total

    prep_kernel<<<2752, 256, 0, stream>>>(
        sp, dense, emb, W1, W2, ww, wb, b3, dxp, W1b, W2b, wide);
    gemm1_8<<<256, 512, 0, stream>>>(
        dxp, W1b, b1, h1, BATCH, HDIM, K1);
    gemm_fused8<<<256, 512, 0, stream>>>(
        h1, W2b, b2, W3, wide, BATCH, HDIM, HDIM);
    sigmoid_kernel<<<BATCH / 256, 256, 0, stream>>>(wide, out);
}

// Round 4
// 159.088 us; speedup vs baseline: 1.0543x; 1.0543x over previous
//
#include <hip/hip_runtime.h>
#include <stdint.h>

// ---------------------------------------------------------------------------
// WideAndDeep: B=16384, F=3, C=256, D=64, H=1024, ND=13
// R18: revert R17's peeled tail (regressed +7us: tail lost barrier pacing).
// Main loop = R16's uniform 8-phase schedule with wrap dead-loads (proven
// 160.7us). NEW: gemm1 A-staging gathers directly from L2-resident
// emb_bf16 (96KB) via per-lane global_load_lds source addresses + a 2MB
// dense-tail table; dxp (8.4MB write + 8.4MB read) eliminated. Sparse idx
// packed in scalars (pk = s0|s1<<8|s2<<16, selected by kt>>6 shifts) -- no
// runtime-indexed arrays. sp preloads drained by vmcnt(0) BEFORE prologue
// so the counted-vmcnt FIFO discipline is preserved. Bit-identical math.
// 8-phase stage order per iter (1 half-tile = 2 global_load_lds/thread/phase):
//   p1:A.O.h0  p2:A.O.h1  p3:B.E.h0  p4:B.E.h1[vmcnt4]
//   p5:A.E.h0  p6:A.E.h1  p7:B.O.h0  p8:B.O.h1[vmcnt4]
// FIFO: vmcnt(4)@p4 retires {B.O prev, A.O} (read p5-p8); vmcnt(4)@p8
// retires {B.E,A.E next} (read next p1-p4). Wrap loads (last iter) re-read
// tile 0 (in-bounds, cache-absorbed) to keep the schedule uniform.
// ---------------------------------------------------------------------------

#define BATCH 16384
#define HDIM 1024
#define K1 256
#define DEEP_IN 205

typedef short bf16x8 __attribute__((ext_vector_type(8)));
typedef float f32x4 __attribute__((ext_vector_type(4)));
typedef uint16_t u16x8 __attribute__((ext_vector_type(8)));
typedef uint16_t u16x4 __attribute__((ext_vector_type(4)));

__device__ __forceinline__ uint16_t f2bf(float f) {
    uint32_t x;
    __builtin_memcpy(&x, &f, 4);
    uint32_t r = (x + 0x7fffu + ((x >> 16) & 1u)) >> 16;
    return (uint16_t)r;
}

__device__ __forceinline__ void async_ld16(const uint16_t* g, uint16_t* l) {
    __builtin_amdgcn_global_load_lds(
        (const __attribute__((address_space(1))) uint32_t*)g,
        (__attribute__((address_space(3))) uint32_t*)l, 16, 0, 0);
}

// ---------------------------------------------------------------------------
// prep: everything the GEMMs need, one elementwise kernel.
//   [0, 24)      : emb -> emb_bf16 (49152 elems, x8)
//   [24, 536)    : dtail [B][64] bf16: cols 0..12 = dense, 13..63 = 0 (x8)
//   [536, 664)   : W1 -> bf16, 205 -> 256 K-pad (x8)
//   [664, 1176)  : W2 -> bf16 (x8)
//   [1176, 1240) : wide path (sparse gathers + dense dot) + b3 seed
// ---------------------------------------------------------------------------
__global__ __launch_bounds__(256) void prep_kernel(
    const int* __restrict__ sp, const float* __restrict__ dense,
    const float* __restrict__ emb, const float* __restrict__ W1,
    const float* __restrict__ W2, const float* __restrict__ ww,
    const float* __restrict__ wb, const float* __restrict__ b3,
    uint16_t* __restrict__ embb, uint16_t* __restrict__ dtail,
    uint16_t* __restrict__ W1b, uint16_t* __restrict__ W2b,
    float* __restrict__ wide)
{
    const int bid = blockIdx.x;
    const int tid = threadIdx.x;
    if (bid < 24) {                        // ---- emb -> bf16 (3*256*64 = 49152)
        int k = bid * 256 + tid;           // < 6144 vec8
        const float* src = emb + (size_t)k * 8;
        float4 v0 = *(const float4*)src;
        float4 v1 = *(const float4*)(src + 4);
        u16x8 o;
        o[0] = f2bf(v0.x); o[1] = f2bf(v0.y); o[2] = f2bf(v0.z); o[3] = f2bf(v0.w);
        o[4] = f2bf(v1.x); o[5] = f2bf(v1.y); o[6] = f2bf(v1.z); o[7] = f2bf(v1.w);
        *(u16x8*)(embb + (size_t)k * 8) = o;
    } else if (bid < 536) {                // ---- dense tail [16384][64]
        int idx = (bid - 24) * 256 + tid;  // < 131072 vec8
        int b = idx >> 3, c0 = (idx & 7) * 8;
        u16x8 o;
#pragma unroll
        for (int t = 0; t < 8; t++) {
            int c = c0 + t;
            o[t] = (c < 13) ? f2bf(dense[b * 13 + c]) : (uint16_t)0;
        }
        *(u16x8*)(dtail + (size_t)b * 64 + c0) = o;
    } else if (bid < 664) {                // ---- W1 convert, 205 -> 256
        int idx = (bid - 536) * 256 + tid;     // < 32768
        int n = idx >> 5, c0 = (idx & 31) * 8;
        u16x8 o;
#pragma unroll
        for (int t = 0; t < 8; t++) {
            int c = c0 + t;
            o[t] = (c < DEEP_IN) ? f2bf(W1[n * DEEP_IN + c]) : (uint16_t)0;
        }
        *(u16x8*)(W1b + (size_t)n * K1 + c0) = o;
    } else if (bid < 1176) {               // ---- W2 convert (x8)
        int k = (bid - 664) * 256 + tid;       // < 131072
        const float* src = W2 + (size_t)k * 8;
        float4 v0 = *(const float4*)src;
        float4 v1 = *(const float4*)(src + 4);
        u16x8 o;
        o[0] = f2bf(v0.x); o[1] = f2bf(v0.y); o[2] = f2bf(v0.z); o[3] = f2bf(v0.w);
        o[4] = f2bf(v1.x); o[5] = f2bf(v1.y); o[6] = f2bf(v1.z); o[7] = f2bf(v1.w);
        *(u16x8*)(W2b + (size_t)k * 8) = o;
    } else {                               // ---- wide path (+ b3 seed)
        int b = (bid - 1176) * 256 + tid;      // < 16384
        int s0 = sp[b * 3], s1 = sp[b * 3 + 1], s2 = sp[b * 3 + 2];
        float w = wb[0] + b3[0];
        w += ww[s0] + ww[256 + s1] + ww[512 + s2];
        w += ww[768    + s0 * 3 + s1];
        w += ww[66304  + s0 * 3 + s2];
        w += ww[131840 + s1 * 3 + s2];
        w += ww[197376 + (s0 * 3 + s1) * 3 + s2];
        const float* wd = ww + 16974592;
        float acc2 = 0.f;
#pragma unroll
        for (int j = 0; j < 13; j++) acc2 += dense[b * 13 + j] * wd[j];
        wide[b] = w + acc2;
    }
}

// ---------------------------------------------------------------------------
// Shared 8-phase GEMM core. 256x256 tile, 8 waves 2m x 4n, wave tile 128x64,
// BK=64, 128 KiB LDS (2 K-tile dbuf). LDS element map: AE=0 AO=16384
// BE=32768 BO=49152; each region [2 halves][128 rows][64 cols], row r's
// column bytes XOR-swizzled by (r&7)<<4 (inverse-swizzled global source,
// linear global_load_lds dest). Raw s_barrier; vmcnt(4) only at p4 & p8.
// Per-kernel STG8A/STG8B macros supply the staging source addresses.
// ---------------------------------------------------------------------------
#define BAR8() do { asm volatile("" ::: "memory");                             \
    __builtin_amdgcn_s_barrier();                                              \
    asm volatile("" ::: "memory"); } while (0)
#define VM4() asm volatile("s_waitcnt vmcnt(4)" ::: "memory")
#define VM0() asm volatile("s_waitcnt vmcnt(0)" ::: "memory")

#define LDA8(base, msub) do {                                                  \
    _Pragma("unroll") for (int mt = 0; mt < 4; mt++) {                         \
        int ro_ = (base) + ((msub) * 64 + mt * 16) * 64;                       \
        af[mt][0] = *(const bf16x8*)&lds[ro_ + kc0];                           \
        af[mt][1] = *(const bf16x8*)&lds[ro_ + kc1];                           \
    } } while (0)

#define LDB8(dst, base, nsub) do {                                             \
    _Pragma("unroll") for (int nt = 0; nt < 2; nt++) {                         \
        int ro_ = (base) + ((nsub) * 32 + nt * 16) * 64;                       \
        dst[nt][0] = *(const bf16x8*)&lds[ro_ + kc0];                          \
        dst[nt][1] = *(const bf16x8*)&lds[ro_ + kc1];                          \
    } } while (0)

#define MM8(msub, nsub, BF) do {                                               \
    __builtin_amdgcn_s_setprio(1);                                             \
    _Pragma("unroll") for (int mt = 0; mt < 4; mt++)                           \
    _Pragma("unroll") for (int nt = 0; nt < 2; nt++) {                         \
        acc[(msub)*4+mt][(nsub)*2+nt] = __builtin_amdgcn_mfma_f32_16x16x32_bf16( \
            af[mt][0], BF[nt][0], acc[(msub)*4+mt][(nsub)*2+nt], 0, 0, 0);     \
        acc[(msub)*4+mt][(nsub)*2+nt] = __builtin_amdgcn_mfma_f32_16x16x32_bf16( \
            af[mt][1], BF[nt][1], acc[(msub)*4+mt][(nsub)*2+nt], 0, 0, 0);     \
    }                                                                          \
    __builtin_amdgcn_s_setprio(0); } while (0)

#define GEMM8_DECLS()                                                          \
    const int tid = threadIdx.x;                                               \
    const int lane = tid & 63, wave = tid >> 6;                                \
    const int wm = wave >> 2, wn = wave & 3;                                   \
    const int id = blockIdx.x;                                                 \
    const int wg = (id & 7) * 32 + (id >> 3);                                  \
    const int by = wg >> 2, bx = wg & 3;                                       \
    const int bm = by * 256, bn = bx * 256;                                    \
    const int lam = lane & 15, lad = lane >> 4;                                \
    const int sw = (lane & 7) << 4;                                            \
    const int kc0 = ((lad * 16) ^ sw) >> 1;                                    \
    const int kc1 = ((64 + lad * 16) ^ sw) >> 1;                               \
    const int aBE = wm * 8192 + lam * 64;                                      \
    const int aBO = aBE + 16384;                                               \
    const int bBE = 32768 + (wn >> 1) * 8192 + ((wn & 1) * 64 + lam) * 64;     \
    const int bBO = bBE + 16384;                                               \
    const int trow = tid >> 3;                                                 \
    const int csel = ((tid & 7) ^ (trow & 7)) << 3;

// R16 main loop: uniform 8-phase schedule, wrap dead-loads keep pacing.
#define GEMM8_MAIN()                                                           \
    f32x4 acc[8][4];                                                           \
    _Pragma("unroll") for (int i = 0; i < 8; i++)                              \
        _Pragma("unroll") for (int j = 0; j < 4; j++) acc[i][j] = (f32x4)0.f;  \
    bf16x8 af[4][2], bf0[2][2], bf1[2][2];                                     \
    const int NT = K >> 6;                                                     \
    const int NI = K >> 7;                                                     \
    STG8A(0, 0, 0);     STG8A(0, 1, 0);                                        \
    STG8B(32768, 0, 0); STG8B(32768, 1, 0);                                    \
    STG8B(49152, 0, 64); STG8B(49152, 1, 64);                                  \
    VM4();                                                                     \
    BAR8();                                                                    \
    for (int it = 0; it < NI; ++it) {                                          \
        const int k1 = (2 * it + 1) * 64;                                      \
        const int t2 = 2 * it + 2, t3 = 2 * it + 3;                            \
        const int k2 = (t2 < NT ? t2 : 0) * 64;                                \
        const int k3 = (t3 < NT ? t3 : 0) * 64;                                \
        LDA8(aBE, 0); LDB8(bf0, bBE, 0); STG8A(16384, 0, k1);                  \
        BAR8(); MM8(0, 0, bf0); BAR8();                                        \
        LDB8(bf1, bBE, 1); STG8A(16384, 1, k1);                                \
        BAR8(); MM8(0, 1, bf1); BAR8();                                        \
        LDA8(aBE, 1); STG8B(32768, 0, k2);                                     \
        BAR8(); MM8(1, 1, bf1); BAR8();                                        \
        STG8B(32768, 1, k2);                                                   \
        BAR8(); MM8(1, 0, bf0); VM4(); BAR8();                                 \
        LDA8(aBO, 0); LDB8(bf0, bBO, 0); STG8A(0, 0, k2);                      \
        BAR8(); MM8(0, 0, bf0); BAR8();                                        \
        LDB8(bf1, bBO, 1); STG8A(0, 1, k2);                                    \
        BAR8(); MM8(0, 1, bf1); BAR8();                                        \
        LDA8(aBO, 1); STG8B(49152, 0, k3);                                     \
        BAR8(); MM8(1, 1, bf1); BAR8();                                        \
        STG8B(49152, 1, k3);                                                   \
        BAR8(); MM8(1, 0, bf0); VM4(); BAR8();                                 \
    }

// ---------------------------------------------------------------------------
// gemm1_8: h1 = relu(deep_x @ W1b^T + b1), K=256 (zero-padded).
// A-staging sources: k-tiles 0..2 gather from emb_bf16 [f][256][64] (row via
// packed sp scalar PKh_j, selected by (kt>>6)*8 bit shift -- pure ALU, no
// runtime-indexed arrays); k-tile 3 reads dtail [B][64]. B rows staged
// permuted (prow = 4*(t&15) + (t>>4)) so lane lam's acc cols jn map to
// n = bn + wn*64 + 4*lam + jn -> natural-layout u16x4 packed stores.
// ---------------------------------------------------------------------------
#define ASRC1(pkv, h2, kt) ((kt) < 192                                         \
    ? (embb + (((kt) >> 6) << 14)                                              \
            + ((int)(((pkv) >> (((kt) >> 6) << 3)) & 255u) << 6) + csel)       \
    : (dtail + (size_t)(b0 + (h2) * 64) * 64 + csel))

#define STG8A(regoff, h, kt) do {                                              \
    async_ld16(ASRC1(PK##h##_0, 2*(h), kt),                                    \
               &lds[(regoff) + (h) * 8192 + wave * 512]);                      \
    async_ld16(ASRC1(PK##h##_1, 2*(h)+1, kt),                                  \
               &lds[(regoff) + (h) * 8192 + 4096 + wave * 512]);               \
} while (0)

#define STG8B(regoff, h, kt) do {                                              \
    const uint16_t* g_ = bRow + (size_t)((h) * 128) * (size_t)K + (kt);        \
    async_ld16(g_, &lds[(regoff) + (h) * 8192 + wave * 512]);                  \
    async_ld16(g_ + (size_t)64 * (size_t)K,                                    \
               &lds[(regoff) + (h) * 8192 + 4096 + wave * 512]);               \
} while (0)

__global__ __launch_bounds__(512, 2) void gemm1_8(
    const int* __restrict__ sp, const uint16_t* __restrict__ embb,
    const uint16_t* __restrict__ dtail, const uint16_t* __restrict__ Bw,
    const float* __restrict__ bias, uint16_t* __restrict__ C)
{
    __shared__ __align__(16) uint16_t lds[65536];   // 128 KiB
    GEMM8_DECLS()
    const int K = K1;
    const int b0 = bm + trow;
    // pack sparse ids for the 4 A-row slots (rows b0 + {0,64,128,192})
    const uint32_t PK0_0 = (uint32_t)sp[(b0      ) * 3] |
                           ((uint32_t)sp[(b0      ) * 3 + 1] << 8) |
                           ((uint32_t)sp[(b0      ) * 3 + 2] << 16);
    const uint32_t PK0_1 = (uint32_t)sp[(b0 +  64) * 3] |
                           ((uint32_t)sp[(b0 +  64) * 3 + 1] << 8) |
                           ((uint32_t)sp[(b0 +  64) * 3 + 2] << 16);
    const uint32_t PK1_0 = (uint32_t)sp[(b0 + 128) * 3] |
                           ((uint32_t)sp[(b0 + 128) * 3 + 1] << 8) |
                           ((uint32_t)sp[(b0 + 128) * 3 + 2] << 16);
    const uint32_t PK1_1 = (uint32_t)sp[(b0 + 192) * 3] |
                           ((uint32_t)sp[(b0 + 192) * 3 + 1] << 8) |
                           ((uint32_t)sp[(b0 + 192) * 3 + 2] << 16);
    const int prow = 4 * (trow & 15) + (trow >> 4);
    const uint16_t* bRow = Bw + (size_t)(bn + prow) * K + csel;
    VM0();   // drain sp loads: counted-vmcnt FIFO must start clean
    GEMM8_MAIN()

    float bv[4];
#pragma unroll
    for (int jn = 0; jn < 4; jn++) bv[jn] = bias[bn + wn * 64 + 4 * lam + jn];
#pragma unroll
    for (int im = 0; im < 8; im++) {
#pragma unroll
        for (int r = 0; r < 4; r++) {
            int m = bm + wm * 128 + im * 16 + lad * 4 + r;
            u16x4 o;
#pragma unroll
            for (int jn = 0; jn < 4; jn++)
                o[jn] = f2bf(fmaxf(acc[im][jn][r] + bv[jn], 0.f));
            *(u16x4*)&C[(size_t)m * HDIM + bn + wn * 64 + 4 * lam] = o;
        }
    }
}

#undef STG8A
#undef STG8B

// ---------------------------------------------------------------------------
// gemm_fused8: per-row partial of relu(acc + b2) . W3 -> atomicAdd(outacc).
// (B staged unpermuted; n-permutation irrelevant to the reduction.)
// ---------------------------------------------------------------------------
#define STG8A(regoff, h, kt) do {                                              \
    const uint16_t* g_ = aRow + (size_t)((h) * 128) * (size_t)K + (kt);        \
    async_ld16(g_, &lds[(regoff) + (h) * 8192 + wave * 512]);                  \
    async_ld16(g_ + (size_t)64 * (size_t)K,                                    \
               &lds[(regoff) + (h) * 8192 + 4096 + wave * 512]);               \
} while (0)

#define STG8B(regoff, h, kt) do {                                              \
    const uint16_t* g_ = bRow + (size_t)((h) * 128) * (size_t)K + (kt);        \
    async_ld16(g_, &lds[(regoff) + (h) * 8192 + wave * 512]);                  \
    async_ld16(g_ + (size_t)64 * (size_t)K,                                    \
               &lds[(regoff) + (h) * 8192 + 4096 + wave * 512]);               \
} while (0)

__global__ __launch_bounds__(512, 2) void gemm_fused8(
    const uint16_t* __restrict__ A, const uint16_t* __restrict__ Bw,
    const float* __restrict__ bias, const float* __restrict__ W3,
    float* __restrict__ outacc, int M, int N, int K)
{
    __shared__ __align__(16) uint16_t lds[65536];   // 128 KiB
    GEMM8_DECLS()
    const uint16_t* aRow = A + (size_t)(bm + trow) * K + csel;
    const uint16_t* bRow = Bw + (size_t)(bn + trow) * K + csel;
    GEMM8_MAIN()

    float bv[4], w3v[4];
#pragma unroll
    for (int jn = 0; jn < 4; jn++) {
        int n = bn + wn * 64 + jn * 16 + lam;
        bv[jn] = bias[n];
        w3v[jn] = W3[n];
    }
#pragma unroll
    for (int im = 0; im < 8; im++) {
#pragma unroll
        for (int r = 0; r < 4; r++) {
            float pt = 0.f;
#pragma unroll
            for (int jn = 0; jn < 4; jn++)
                pt += fmaxf(acc[im][jn][r] + bv[jn], 0.f) * w3v[jn];
            pt += __shfl_xor(pt, 1);
            pt += __shfl_xor(pt, 2);
            pt += __shfl_xor(pt, 4);
            pt += __shfl_xor(pt, 8);
            if (lam == 0) {
                int m = bm + wm * 128 + im * 16 + lad * 4 + r;
                atomicAdd(&outacc[m], pt);
            }
        }
    }
}

#undef STG8A
#undef STG8B

// ---------------------------------------------------------------------------
// Sigmoid over the accumulated logits. Grid 64 x 256.
// ---------------------------------------------------------------------------
__global__ __launch_bounds__(256) void sigmoid_kernel(
    const float* __restrict__ outacc, float* __restrict__ out)
{
    int b = blockIdx.x * 256 + threadIdx.x;
    out[b] = 1.f / (1.f + __expf(-outacc[b]));
}

// ---------------------------------------------------------------------------
extern "C" void kernel_launch(void* const* d_in, const int* in_sizes, int n_in,
                              void* d_out, int out_size, void* d_ws, size_t ws_size,
                              hipStream_t stream) {
    const int*   sp    = (const int*)d_in[0];
    const float* dense = (const float*)d_in[1];
    const float* ww    = (const float*)d_in[2];
    const float* wb    = (const float*)d_in[3];
    const float* emb   = (const float*)d_in[4];
    const float* W1    = (const float*)d_in[5];
    const float* b1    = (const float*)d_in[6];
    const float* W2    = (const float*)d_in[7];
    const float* b2    = (const float*)d_in[8];
    const float* W3    = (const float*)d_in[9];
    const float* b3    = (const float*)d_in[10];
    float* out = (float*)d_out;

    char* ws = (char*)d_ws;
    float*    wide  = (float*)ws;                      //     65,536 B
    uint16_t* embb  = (uint16_t*)(ws + 65536);         //     98,304 B (3x256x64)
    uint16_t* dtail = (uint16_t*)(ws + 163840);        //  2,097,152 B (16384x64)
    uint16_t* W1b   = (uint16_t*)(ws + 2260992);       //    524,288 B (1024x256)
    uint16_t* W2b   = (uint16_t*)(ws + 2785280);       //  2,097,152 B
    uint16_t* h1    = (uint16_t*)(ws + 4882432);       // 33,554,432 B -> 38,436,864 total

    prep_kernel<<<1240, 256, 0, stream>>>(
        sp, dense, emb, W1, W2, ww, wb, b3, embb, dtail, W1b, W2b, wide);
    gemm1_8<<<256, 512, 0, stream>>>(
        sp, embb, dtail, W1b, b1, h1);
    gemm_fused8<<<256, 512, 0, stream>>>(
        h1, W2b, b2, W3, wide, BATCH, HDIM, HDIM);
    sigmoid_kernel<<<BATCH / 256, 256, 0, stream>>>(wide, out);
}